// Round 1
// baseline (562.858 us; speedup 1.0000x reference)
//
#include <hip/hip_runtime.h>
#include <hip/hip_bf16.h>

// Problem constants (match reference)
#define NN 50000
#define EE 800000
#define EP (EE + NN)        // edges + self loops = 850000
#define DIN 128
#define HID 32
#define HEADS 8
#define C1 (HEADS * HID)    // 256
#define DOUT 16

// ---------------------------------------------------------------------------
// CSR build: deg init (self loop = 1), count, scan (3 kernels), scatter
// ---------------------------------------------------------------------------
__global__ void k_initdeg(int* __restrict__ deg) {
    int i = blockIdx.x * 256 + threadIdx.x;
    if (i < NN) deg[i] = 1;   // self loop
}

__global__ void k_countdeg(const int* __restrict__ ei, int* __restrict__ deg) {
    int i = blockIdx.x * 256 + threadIdx.x;
    if (i < EE) atomicAdd(&deg[ei[EE + i]], 1);
}

__global__ void k_scan1(const int* __restrict__ deg, int* __restrict__ row_ptr,
                        int* __restrict__ aux) {
    __shared__ int s[1024];
    int t = threadIdx.x;
    int i = blockIdx.x * 1024 + t;
    int v = (i < NN) ? deg[i] : 0;
    int orig = v;
    s[t] = v;
    for (int off = 1; off < 1024; off <<= 1) {
        __syncthreads();
        int u = (t >= off) ? s[t - off] : 0;
        __syncthreads();
        s[t] += u;
    }
    __syncthreads();
    if (i < NN) row_ptr[i] = s[t] - orig;       // exclusive within block
    if (t == 1023) aux[blockIdx.x] = s[t];      // block total
}

__global__ void k_scan2(int* __restrict__ aux, int nb) {
    if (threadIdx.x == 0 && blockIdx.x == 0) {
        int run = 0;
        for (int b = 0; b < nb; b++) { int v = aux[b]; aux[b] = run; run += v; }
    }
}

__global__ void k_scan3(int* __restrict__ row_ptr, const int* __restrict__ aux,
                        int* __restrict__ wp) {
    int i = blockIdx.x * 256 + threadIdx.x;
    if (i < NN) {
        int v = row_ptr[i] + aux[i >> 10];
        row_ptr[i] = v;
        wp[i] = v;
    }
    if (i == 0) row_ptr[NN] = EP;
}

__global__ void k_scatter(const int* __restrict__ ei, int* __restrict__ wp,
                          int* __restrict__ esrc) {
    int i = blockIdx.x * 256 + threadIdx.x;
    if (i < EE) {
        int s = ei[i];
        int d = ei[EE + i];
        int pos = atomicAdd(&wp[d], 1);
        esrc[pos] = s;
    } else if (i < EP) {
        int n = i - EE;
        int pos = atomicAdd(&wp[n], 1);
        esrc[pos] = n;   // self loop
    }
}

// ---------------------------------------------------------------------------
// GEMM1: h1[N,256] = x[N,128] @ W1[128,256]  (fp32, 128x128 tile, 8x8/thread)
// ---------------------------------------------------------------------------
__global__ __launch_bounds__(256) void k_gemm1(const float* __restrict__ x,
                                               const float* __restrict__ W1,
                                               float* __restrict__ h1) {
    __shared__ float As[32][132];   // [k][node] transposed, padded
    __shared__ float Bs[32][132];   // [k][col], padded
    int tid = threadIdx.x;
    int tx = tid & 15, ty = tid >> 4;
    int nb0 = blockIdx.x * 128;
    int cb0 = blockIdx.y * 128;
    float acc[8][8];
    #pragma unroll
    for (int i = 0; i < 8; i++)
        #pragma unroll
        for (int j = 0; j < 8; j++) acc[i][j] = 0.0f;

    int qa = tid & 7, ra = tid >> 3;        // A loader: k group, node
    int cb_l = (tid & 31) * 4, kr = tid >> 5; // B loader

    for (int kc = 0; kc < 128; kc += 32) {
        // load A tile: 128 nodes x 32 k  (transposed into As[k][node])
        #pragma unroll
        for (int p = 0; p < 4; p++) {
            int n_l = p * 32 + ra;
            int node = nb0 + n_l;
            float4 v = make_float4(0.f, 0.f, 0.f, 0.f);
            if (node < NN) v = *(const float4*)(x + node * DIN + kc + qa * 4);
            As[qa * 4 + 0][n_l] = v.x;
            As[qa * 4 + 1][n_l] = v.y;
            As[qa * 4 + 2][n_l] = v.z;
            As[qa * 4 + 3][n_l] = v.w;
        }
        // load B tile: 32 k x 128 cols
        #pragma unroll
        for (int p = 0; p < 4; p++) {
            int k_b = p * 8 + kr;
            float4 v = *(const float4*)(W1 + (kc + k_b) * C1 + cb0 + cb_l);
            *(float4*)&Bs[k_b][cb_l] = v;
        }
        __syncthreads();
        #pragma unroll
        for (int k = 0; k < 32; k++) {
            float4 a0 = *(const float4*)&As[k][ty * 8];
            float4 a1 = *(const float4*)&As[k][ty * 8 + 4];
            float4 b0 = *(const float4*)&Bs[k][tx * 8];
            float4 b1 = *(const float4*)&Bs[k][tx * 8 + 4];
            float a[8] = {a0.x, a0.y, a0.z, a0.w, a1.x, a1.y, a1.z, a1.w};
            float b[8] = {b0.x, b0.y, b0.z, b0.w, b1.x, b1.y, b1.z, b1.w};
            #pragma unroll
            for (int i = 0; i < 8; i++)
                #pragma unroll
                for (int j = 0; j < 8; j++) acc[i][j] += a[i] * b[j];
        }
        __syncthreads();
    }
    #pragma unroll
    for (int i = 0; i < 8; i++) {
        int node = nb0 + ty * 8 + i;
        if (node < NN) {
            float4 v0 = make_float4(acc[i][0], acc[i][1], acc[i][2], acc[i][3]);
            float4 v1 = make_float4(acc[i][4], acc[i][5], acc[i][6], acc[i][7]);
            float* p = h1 + node * C1 + cb0 + tx * 8;
            *(float4*)p = v0;
            *(float4*)(p + 4) = v1;
        }
    }
}

// ---------------------------------------------------------------------------
// al1: attention logits per (node, head)
// ---------------------------------------------------------------------------
__global__ void k_al1(const float* __restrict__ h1, const float* __restrict__ a1s,
                      const float* __restrict__ a1d, float* __restrict__ al1s,
                      float* __restrict__ al1d) {
    int i = blockIdx.x * 256 + threadIdx.x;
    if (i >= NN * HEADS) return;
    int n = i >> 3, h = i & 7;
    const float4* hp = (const float4*)(h1 + n * C1 + h * HID);
    const float4* as = (const float4*)(a1s + h * HID);
    const float4* ad = (const float4*)(a1d + h * HID);
    float ss = 0.f, sd = 0.f;
    #pragma unroll
    for (int j = 0; j < 8; j++) {
        float4 hv = hp[j], av = as[j], dv = ad[j];
        ss += hv.x * av.x + hv.y * av.y + hv.z * av.z + hv.w * av.w;
        sd += hv.x * dv.x + hv.y * dv.y + hv.z * dv.z + hv.w * dv.w;
    }
    al1s[i] = ss;
    al1d[i] = sd;
}

// ---------------------------------------------------------------------------
// agg1: one wave per dst node. lane L: head = L>>3, channels (L&7)*4 .. +3.
// Computes softmax-weighted sum over incoming edges (no max-subtraction --
// logits are O(+-5), exp is safe), then + b1 and ELU -> helu.
// ---------------------------------------------------------------------------
__global__ __launch_bounds__(256) void k_agg1(const int* __restrict__ row_ptr,
                                              const int* __restrict__ esrc,
                                              const float* __restrict__ h1,
                                              const float* __restrict__ al1s,
                                              const float* __restrict__ al1d,
                                              const float* __restrict__ b1,
                                              float* __restrict__ helu) {
    int wid = (blockIdx.x * 256 + threadIdx.x) >> 6;
    int L = threadIdx.x & 63;
    if (wid >= NN) return;
    int d = wid;
    int h = L >> 3;
    int start = row_ptr[d], end = row_ptr[d + 1];
    float ald = al1d[d * 8 + h];
    float denom = 0.f;
    float4 acc = make_float4(0.f, 0.f, 0.f, 0.f);
    for (int base = start; base < end; base += 64) {
        int mye = (base + L < end) ? esrc[base + L] : 0;
        int cnt = min(64, end - base);
        for (int i = 0; i < cnt; i++) {
            int s = __shfl(mye, i, 64);
            float v = al1s[s * 8 + h] + ald;
            v = v > 0.f ? v : 0.2f * v;
            float w = __expf(v);
            denom += w;
            float4 hv = *(const float4*)(h1 + s * C1 + L * 4);
            acc.x += w * hv.x;
            acc.y += w * hv.y;
            acc.z += w * hv.z;
            acc.w += w * hv.w;
        }
    }
    float inv = 1.0f / (denom + 1e-16f);
    float4 bv = *(const float4*)(b1 + L * 4);
    float o0 = acc.x * inv + bv.x;
    float o1 = acc.y * inv + bv.y;
    float o2 = acc.z * inv + bv.z;
    float o3 = acc.w * inv + bv.w;
    o0 = o0 > 0.f ? o0 : __expf(o0) - 1.0f;
    o1 = o1 > 0.f ? o1 : __expf(o1) - 1.0f;
    o2 = o2 > 0.f ? o2 : __expf(o2) - 1.0f;
    o3 = o3 > 0.f ? o3 : __expf(o3) - 1.0f;
    *(float4*)(helu + d * C1 + L * 4) = make_float4(o0, o1, o2, o3);
}

// ---------------------------------------------------------------------------
// W2 transpose (16KB) so GEMM2 can read contiguous float4 per column
// ---------------------------------------------------------------------------
__global__ void k_transw2(const float* __restrict__ W2, float* __restrict__ W2T) {
    int i = blockIdx.x * 256 + threadIdx.x;
    if (i < C1 * DOUT) {
        int k = i >> 4, c = i & 15;
        W2T[c * C1 + k] = W2[i];
    }
}

// ---------------------------------------------------------------------------
// GEMM2 + al2: 16 lanes per node, one col each; shuffle-reduce al2
// ---------------------------------------------------------------------------
__global__ __launch_bounds__(256) void k_gemm2(const float* __restrict__ helu,
                                               const float* __restrict__ W2T,
                                               const float* __restrict__ a2s,
                                               const float* __restrict__ a2d,
                                               float* __restrict__ h2,
                                               float* __restrict__ al2s,
                                               float* __restrict__ al2d) {
    int gid = blockIdx.x * 256 + threadIdx.x;
    int n = gid >> 4, c = gid & 15;
    if (n >= NN) return;
    const float4* hp = (const float4*)(helu + n * C1);
    const float4* wv = (const float4*)(W2T + c * C1);
    float acc = 0.f;
    #pragma unroll 8
    for (int j = 0; j < 64; j++) {
        float4 h4 = hp[j], w4 = wv[j];
        acc += h4.x * w4.x + h4.y * w4.y + h4.z * w4.z + h4.w * w4.w;
    }
    h2[n * DOUT + c] = acc;
    float ps = acc * a2s[c];
    float pd = acc * a2d[c];
    #pragma unroll
    for (int m = 1; m < 16; m <<= 1) {
        ps += __shfl_xor(ps, m, 64);
        pd += __shfl_xor(pd, m, 64);
    }
    if (c == 0) {
        al2s[n] = ps;
        al2d[n] = pd;
    }
}

// ---------------------------------------------------------------------------
// agg2 + bias + log_softmax: 16 lanes per node (4 nodes/wave)
// ---------------------------------------------------------------------------
__global__ __launch_bounds__(256) void k_agg2(const int* __restrict__ row_ptr,
                                              const int* __restrict__ esrc,
                                              const float* __restrict__ h2,
                                              const float* __restrict__ al2s,
                                              const float* __restrict__ al2d,
                                              const float* __restrict__ b2,
                                              float* __restrict__ out) {
    int gid = blockIdx.x * 256 + threadIdx.x;
    int n = gid >> 4, c = gid & 15;
    if (n >= NN) return;
    int start = row_ptr[n], end = row_ptr[n + 1];
    float ald = al2d[n];
    float acc = 0.f, denom = 0.f;
    for (int idx = start; idx < end; idx++) {
        int s = esrc[idx];
        float v = al2s[s] + ald;
        v = v > 0.f ? v : 0.2f * v;
        float w = __expf(v);
        denom += w;
        acc += w * h2[s * DOUT + c];
    }
    float val = acc / (denom + 1e-16f) + b2[c];
    // log_softmax over the 16 lanes of this node
    float m = val;
    #pragma unroll
    for (int mm = 1; mm < 16; mm <<= 1) m = fmaxf(m, __shfl_xor(m, mm, 64));
    float ex = __expf(val - m);
    float se = ex;
    #pragma unroll
    for (int mm = 1; mm < 16; mm <<= 1) se += __shfl_xor(se, mm, 64);
    out[n * DOUT + c] = val - m - __logf(se);
}

// ---------------------------------------------------------------------------
extern "C" void kernel_launch(void* const* d_in, const int* in_sizes, int n_in,
                              void* d_out, int out_size, void* d_ws, size_t ws_size,
                              hipStream_t stream) {
    const float* x   = (const float*)d_in[0];
    const int*   ei  = (const int*)d_in[1];
    const float* W1  = (const float*)d_in[2];
    const float* a1s = (const float*)d_in[3];
    const float* a1d = (const float*)d_in[4];
    const float* b1  = (const float*)d_in[5];
    const float* W2  = (const float*)d_in[6];
    const float* a2s = (const float*)d_in[7];
    const float* a2d = (const float*)d_in[8];
    const float* b2  = (const float*)d_in[9];
    float* outp = (float*)d_out;

    // workspace layout (all 4B types; d_ws is 256B-aligned)
    float* h1    = (float*)d_ws;            // N*256
    float* helu  = h1 + NN * C1;            // N*256
    float* al1sb = helu + NN * C1;          // N*8
    float* al1db = al1sb + NN * HEADS;      // N*8
    float* h2    = al1db + NN * HEADS;      // N*16
    float* al2sb = h2 + NN * DOUT;          // N
    float* al2db = al2sb + NN;              // N
    float* W2T   = al2db + NN;              // 4096
    int* deg     = (int*)(W2T + C1 * DOUT); // N
    int* row_ptr = deg + NN;                // N+1
    int* wp      = row_ptr + NN + 1;        // N
    int* esrc    = wp + NN;                 // EP
    int* aux     = esrc + EP;               // 64

    const int nscan = (NN + 1023) / 1024;   // 49

    k_initdeg<<<(NN + 255) / 256, 256, 0, stream>>>(deg);
    k_countdeg<<<(EE + 255) / 256, 256, 0, stream>>>(ei, deg);
    k_scan1<<<nscan, 1024, 0, stream>>>(deg, row_ptr, aux);
    k_scan2<<<1, 64, 0, stream>>>(aux, nscan);
    k_scan3<<<(NN + 255) / 256, 256, 0, stream>>>(row_ptr, aux, wp);
    k_scatter<<<(EP + 255) / 256, 256, 0, stream>>>(ei, wp, esrc);

    dim3 g1((NN + 127) / 128, 2);
    k_gemm1<<<g1, 256, 0, stream>>>(x, W1, h1);
    k_al1<<<(NN * HEADS + 255) / 256, 256, 0, stream>>>(h1, a1s, a1d, al1sb, al1db);
    k_agg1<<<(NN * 64) / 256, 256, 0, stream>>>(row_ptr, esrc, h1, al1sb, al1db, b1, helu);

    k_transw2<<<(C1 * DOUT + 255) / 256, 256, 0, stream>>>(W2, W2T);
    k_gemm2<<<(NN * DOUT) / 256, 256, 0, stream>>>(helu, W2T, a2s, a2d, h2, al2sb, al2db);
    k_agg2<<<(NN * DOUT) / 256, 256, 0, stream>>>(row_ptr, esrc, h2, al2sb, al2db, b2, outp);
}

// Round 2
// 450.694 us; speedup vs baseline: 1.2489x; 1.2489x over previous
//
#include <hip/hip_runtime.h>
#include <hip/hip_bf16.h>

// Problem constants (match reference)
#define NN 50000
#define EE 800000
#define EP (EE + NN)        // edges + self loops = 850000
#define DIN 128
#define HID 32
#define HEADS 8
#define C1 (HEADS * HID)    // 256
#define DOUT 16

__device__ inline unsigned short f2bf(float f) {
    __hip_bfloat16 b = __float2bfloat16(f);
    return *reinterpret_cast<unsigned short*>(&b);
}
__device__ inline float bf2f(unsigned short u) {
    union { unsigned int i; float f; } x;
    x.i = ((unsigned int)u) << 16;
    return x.f;
}

// ---------------------------------------------------------------------------
// CSR build: deg init (self loop = 1), count, scan (3 kernels), scatter
// ---------------------------------------------------------------------------
__global__ void k_initdeg(int* __restrict__ deg) {
    int i = blockIdx.x * 256 + threadIdx.x;
    if (i < NN) deg[i] = 1;   // self loop
}

__global__ void k_countdeg(const int* __restrict__ ei, int* __restrict__ deg) {
    int i = blockIdx.x * 256 + threadIdx.x;
    if (i < EE) atomicAdd(&deg[ei[EE + i]], 1);
}

__global__ void k_scan1(const int* __restrict__ deg, int* __restrict__ row_ptr,
                        int* __restrict__ aux) {
    __shared__ int s[1024];
    int t = threadIdx.x;
    int i = blockIdx.x * 1024 + t;
    int v = (i < NN) ? deg[i] : 0;
    int orig = v;
    s[t] = v;
    for (int off = 1; off < 1024; off <<= 1) {
        __syncthreads();
        int u = (t >= off) ? s[t - off] : 0;
        __syncthreads();
        s[t] += u;
    }
    __syncthreads();
    if (i < NN) row_ptr[i] = s[t] - orig;       // exclusive within block
    if (t == 1023) aux[blockIdx.x] = s[t];      // block total
}

__global__ void k_scan2(int* __restrict__ aux, int nb) {
    if (threadIdx.x == 0 && blockIdx.x == 0) {
        int run = 0;
        for (int b = 0; b < nb; b++) { int v = aux[b]; aux[b] = run; run += v; }
    }
}

__global__ void k_scan3(int* __restrict__ row_ptr, const int* __restrict__ aux,
                        int* __restrict__ wp) {
    int i = blockIdx.x * 256 + threadIdx.x;
    if (i < NN) {
        int v = row_ptr[i] + aux[i >> 10];
        row_ptr[i] = v;
        wp[i] = v;
    }
    if (i == 0) row_ptr[NN] = EP;
}

__global__ void k_scatter(const int* __restrict__ ei, int* __restrict__ wp,
                          int* __restrict__ esrc) {
    int i = blockIdx.x * 256 + threadIdx.x;
    if (i < EE) {
        int s = ei[i];
        int d = ei[EE + i];
        int pos = atomicAdd(&wp[d], 1);
        esrc[pos] = s;
    } else if (i < EP) {
        int n = i - EE;
        int pos = atomicAdd(&wp[n], 1);
        esrc[pos] = n;   // self loop
    }
}

// ---------------------------------------------------------------------------
// GEMM1: h1b[N,256](bf16) = x[N,128] @ W1[128,256]  (fp32 compute, 128x128
// tile, 8x8/thread) + fused al1 attention-logit epilogue.
// a1s/a1d are [8][32] flat == indexed directly by global column.
// ---------------------------------------------------------------------------
__global__ __launch_bounds__(256) void k_gemm1(const float* __restrict__ x,
                                               const float* __restrict__ W1,
                                               const float* __restrict__ a1s,
                                               const float* __restrict__ a1d,
                                               unsigned short* __restrict__ h1b,
                                               float* __restrict__ al1s,
                                               float* __restrict__ al1d) {
    __shared__ float As[32][132];   // [k][node] transposed, padded
    __shared__ float Bs[32][132];   // [k][col], padded
    int tid = threadIdx.x;
    int tx = tid & 15, ty = tid >> 4;
    int nb0 = blockIdx.x * 128;
    int cb0 = blockIdx.y * 128;
    float acc[8][8];
    #pragma unroll
    for (int i = 0; i < 8; i++)
        #pragma unroll
        for (int j = 0; j < 8; j++) acc[i][j] = 0.0f;

    int qa = tid & 7, ra = tid >> 3;          // A loader: k group, node
    int cb_l = (tid & 31) * 4, kr = tid >> 5; // B loader

    for (int kc = 0; kc < 128; kc += 32) {
        #pragma unroll
        for (int p = 0; p < 4; p++) {
            int n_l = p * 32 + ra;
            int node = nb0 + n_l;
            float4 v = make_float4(0.f, 0.f, 0.f, 0.f);
            if (node < NN) v = *(const float4*)(x + node * DIN + kc + qa * 4);
            As[qa * 4 + 0][n_l] = v.x;
            As[qa * 4 + 1][n_l] = v.y;
            As[qa * 4 + 2][n_l] = v.z;
            As[qa * 4 + 3][n_l] = v.w;
        }
        #pragma unroll
        for (int p = 0; p < 4; p++) {
            int k_b = p * 8 + kr;
            float4 v = *(const float4*)(W1 + (kc + k_b) * C1 + cb0 + cb_l);
            *(float4*)&Bs[k_b][cb_l] = v;
        }
        __syncthreads();
        #pragma unroll
        for (int k = 0; k < 32; k++) {
            float4 a0 = *(const float4*)&As[k][ty * 8];
            float4 a1 = *(const float4*)&As[k][ty * 8 + 4];
            float4 b0 = *(const float4*)&Bs[k][tx * 8];
            float4 b1 = *(const float4*)&Bs[k][tx * 8 + 4];
            float a[8] = {a0.x, a0.y, a0.z, a0.w, a1.x, a1.y, a1.z, a1.w};
            float b[8] = {b0.x, b0.y, b0.z, b0.w, b1.x, b1.y, b1.z, b1.w};
            #pragma unroll
            for (int i = 0; i < 8; i++)
                #pragma unroll
                for (int j = 0; j < 8; j++) acc[i][j] += a[i] * b[j];
        }
        __syncthreads();
    }

    // epilogue: bf16 store + fused al1 (head = 32 cols = 4 threads' strips)
    float a_s[8], a_d[8];
    int cg0 = cb0 + tx * 8;
    #pragma unroll
    for (int j = 0; j < 8; j++) {
        a_s[j] = a1s[cg0 + j];
        a_d[j] = a1d[cg0 + j];
    }
    int head = cg0 >> 5;
    #pragma unroll
    for (int i = 0; i < 8; i++) {
        int node = nb0 + ty * 8 + i;
        if (node < NN) {
            uint4 pk;
            pk.x = (unsigned)f2bf(acc[i][0]) | ((unsigned)f2bf(acc[i][1]) << 16);
            pk.y = (unsigned)f2bf(acc[i][2]) | ((unsigned)f2bf(acc[i][3]) << 16);
            pk.z = (unsigned)f2bf(acc[i][4]) | ((unsigned)f2bf(acc[i][5]) << 16);
            pk.w = (unsigned)f2bf(acc[i][6]) | ((unsigned)f2bf(acc[i][7]) << 16);
            *(uint4*)(h1b + node * C1 + cg0) = pk;
        }
        float ps = 0.f, pd = 0.f;
        #pragma unroll
        for (int j = 0; j < 8; j++) {
            ps += acc[i][j] * a_s[j];
            pd += acc[i][j] * a_d[j];
        }
        ps += __shfl_xor(ps, 1, 64); ps += __shfl_xor(ps, 2, 64);
        pd += __shfl_xor(pd, 1, 64); pd += __shfl_xor(pd, 2, 64);
        if ((tx & 3) == 0 && node < NN) {
            al1s[node * 8 + head] = ps;
            al1d[node * 8 + head] = pd;
        }
    }
}

// ---------------------------------------------------------------------------
// agg1: one wave per dst node. lane L: head = L>>3, channels (L&7)*4 .. +3.
// Softmax-weighted sum over incoming edges (no max-subtraction: logits O(+-5)),
// + b1, ELU -> helu_b (bf16). Gathers bf16 h1 rows (512 B/edge).
// ---------------------------------------------------------------------------
__global__ __launch_bounds__(256) void k_agg1(const int* __restrict__ row_ptr,
                                              const int* __restrict__ esrc,
                                              const unsigned short* __restrict__ h1b,
                                              const float* __restrict__ al1s,
                                              const float* __restrict__ al1d,
                                              const float* __restrict__ b1,
                                              unsigned short* __restrict__ helu_b) {
    int wid = (blockIdx.x * 256 + threadIdx.x) >> 6;
    int L = threadIdx.x & 63;
    if (wid >= NN) return;
    int d = wid;
    int h = L >> 3;
    int start = row_ptr[d], end = row_ptr[d + 1];
    float ald = al1d[d * 8 + h];
    float denom = 0.f;
    float4 acc = make_float4(0.f, 0.f, 0.f, 0.f);
    for (int base = start; base < end; base += 64) {
        int mye = (base + L < end) ? esrc[base + L] : 0;
        int cnt = min(64, end - base);
        for (int i = 0; i < cnt; i++) {
            int s = __shfl(mye, i, 64);
            float v = al1s[s * 8 + h] + ald;
            v = v > 0.f ? v : 0.2f * v;
            float w = __expf(v);
            denom += w;
            uint2 hv = *(const uint2*)(h1b + s * C1 + L * 4);
            acc.x += w * bf2f((unsigned short)(hv.x & 0xffff));
            acc.y += w * bf2f((unsigned short)(hv.x >> 16));
            acc.z += w * bf2f((unsigned short)(hv.y & 0xffff));
            acc.w += w * bf2f((unsigned short)(hv.y >> 16));
        }
    }
    float inv = 1.0f / (denom + 1e-16f);
    float4 bv = *(const float4*)(b1 + L * 4);
    float o0 = acc.x * inv + bv.x;
    float o1 = acc.y * inv + bv.y;
    float o2 = acc.z * inv + bv.z;
    float o3 = acc.w * inv + bv.w;
    o0 = o0 > 0.f ? o0 : __expf(o0) - 1.0f;
    o1 = o1 > 0.f ? o1 : __expf(o1) - 1.0f;
    o2 = o2 > 0.f ? o2 : __expf(o2) - 1.0f;
    o3 = o3 > 0.f ? o3 : __expf(o3) - 1.0f;
    uint2 pk;
    pk.x = (unsigned)f2bf(o0) | ((unsigned)f2bf(o1) << 16);
    pk.y = (unsigned)f2bf(o2) | ((unsigned)f2bf(o3) << 16);
    *(uint2*)(helu_b + d * C1 + L * 4) = pk;
}

// ---------------------------------------------------------------------------
// W2 transpose (16KB) so GEMM2 can read contiguous float4 per column
// ---------------------------------------------------------------------------
__global__ void k_transw2(const float* __restrict__ W2, float* __restrict__ W2T) {
    int i = blockIdx.x * 256 + threadIdx.x;
    if (i < C1 * DOUT) {
        int k = i >> 4, c = i & 15;
        W2T[c * C1 + k] = W2[i];
    }
}

// ---------------------------------------------------------------------------
// GEMM2 + al2: 16 lanes per node, one col each; shuffle-reduce al2.
// Reads bf16 helu, writes bf16 h2.
// ---------------------------------------------------------------------------
__global__ __launch_bounds__(256) void k_gemm2(const unsigned short* __restrict__ helu_b,
                                               const float* __restrict__ W2T,
                                               const float* __restrict__ a2s,
                                               const float* __restrict__ a2d,
                                               unsigned short* __restrict__ h2b,
                                               float* __restrict__ al2s,
                                               float* __restrict__ al2d) {
    int gid = blockIdx.x * 256 + threadIdx.x;
    int n = gid >> 4, c = gid & 15;
    if (n >= NN) return;
    const uint4* hp = (const uint4*)(helu_b + n * C1);   // 8 bf16 per load
    const float4* wv = (const float4*)(W2T + c * C1);
    float acc = 0.f;
    #pragma unroll 8
    for (int j = 0; j < 32; j++) {
        uint4 hh = hp[j];
        float4 w0 = wv[2 * j], w1 = wv[2 * j + 1];
        acc += bf2f((unsigned short)(hh.x & 0xffff)) * w0.x;
        acc += bf2f((unsigned short)(hh.x >> 16))    * w0.y;
        acc += bf2f((unsigned short)(hh.y & 0xffff)) * w0.z;
        acc += bf2f((unsigned short)(hh.y >> 16))    * w0.w;
        acc += bf2f((unsigned short)(hh.z & 0xffff)) * w1.x;
        acc += bf2f((unsigned short)(hh.z >> 16))    * w1.y;
        acc += bf2f((unsigned short)(hh.w & 0xffff)) * w1.z;
        acc += bf2f((unsigned short)(hh.w >> 16))    * w1.w;
    }
    h2b[n * DOUT + c] = f2bf(acc);
    float ps = acc * a2s[c];
    float pd = acc * a2d[c];
    #pragma unroll
    for (int m = 1; m < 16; m <<= 1) {
        ps += __shfl_xor(ps, m, 64);
        pd += __shfl_xor(pd, m, 64);
    }
    if (c == 0) {
        al2s[n] = ps;
        al2d[n] = pd;
    }
}

// ---------------------------------------------------------------------------
// agg2 + bias + log_softmax: 16 lanes per node (4 nodes/wave), bf16 h2 gather
// ---------------------------------------------------------------------------
__global__ __launch_bounds__(256) void k_agg2(const int* __restrict__ row_ptr,
                                              const int* __restrict__ esrc,
                                              const unsigned short* __restrict__ h2b,
                                              const float* __restrict__ al2s,
                                              const float* __restrict__ al2d,
                                              const float* __restrict__ b2,
                                              float* __restrict__ out) {
    int gid = blockIdx.x * 256 + threadIdx.x;
    int n = gid >> 4, c = gid & 15;
    if (n >= NN) return;
    int start = row_ptr[n], end = row_ptr[n + 1];
    float ald = al2d[n];
    float acc = 0.f, denom = 0.f;
    for (int idx = start; idx < end; idx++) {
        int s = esrc[idx];
        float v = al2s[s] + ald;
        v = v > 0.f ? v : 0.2f * v;
        float w = __expf(v);
        denom += w;
        acc += w * bf2f(h2b[s * DOUT + c]);
    }
    float val = acc / (denom + 1e-16f) + b2[c];
    float m = val;
    #pragma unroll
    for (int mm = 1; mm < 16; mm <<= 1) m = fmaxf(m, __shfl_xor(m, mm, 64));
    float ex = __expf(val - m);
    float se = ex;
    #pragma unroll
    for (int mm = 1; mm < 16; mm <<= 1) se += __shfl_xor(se, mm, 64);
    out[n * DOUT + c] = val - m - __logf(se);
}

// ---------------------------------------------------------------------------
extern "C" void kernel_launch(void* const* d_in, const int* in_sizes, int n_in,
                              void* d_out, int out_size, void* d_ws, size_t ws_size,
                              hipStream_t stream) {
    const float* x   = (const float*)d_in[0];
    const int*   ei  = (const int*)d_in[1];
    const float* W1  = (const float*)d_in[2];
    const float* a1s = (const float*)d_in[3];
    const float* a1d = (const float*)d_in[4];
    const float* b1  = (const float*)d_in[5];
    const float* W2  = (const float*)d_in[6];
    const float* a2s = (const float*)d_in[7];
    const float* a2d = (const float*)d_in[8];
    const float* b2  = (const float*)d_in[9];
    float* outp = (float*)d_out;

    // workspace layout
    unsigned short* h1b    = (unsigned short*)d_ws;      // N*256 bf16
    unsigned short* helu_b = h1b + NN * C1;              // N*256 bf16
    unsigned short* h2b    = helu_b + NN * C1;           // N*16 bf16
    float* al1sb = (float*)(h2b + NN * DOUT);            // N*8
    float* al1db = al1sb + NN * HEADS;                   // N*8
    float* al2sb = al1db + NN * HEADS;                   // N
    float* al2db = al2sb + NN;                           // N
    float* W2T   = al2db + NN;                           // 4096
    int* deg     = (int*)(W2T + C1 * DOUT);              // N
    int* row_ptr = deg + NN;                             // N+1
    int* wp      = row_ptr + NN + 1;                     // N
    int* esrc    = wp + NN;                              // EP
    int* aux     = esrc + EP;                            // 64

    const int nscan = (NN + 1023) / 1024;   // 49

    k_initdeg<<<(NN + 255) / 256, 256, 0, stream>>>(deg);
    k_countdeg<<<(EE + 255) / 256, 256, 0, stream>>>(ei, deg);
    k_scan1<<<nscan, 1024, 0, stream>>>(deg, row_ptr, aux);
    k_scan2<<<1, 64, 0, stream>>>(aux, nscan);
    k_scan3<<<(NN + 255) / 256, 256, 0, stream>>>(row_ptr, aux, wp);
    k_scatter<<<(EP + 255) / 256, 256, 0, stream>>>(ei, wp, esrc);

    dim3 g1((NN + 127) / 128, 2);
    k_gemm1<<<g1, 256, 0, stream>>>(x, W1, a1s, a1d, h1b, al1sb, al1db);
    k_agg1<<<(NN * 64 + 255) / 256, 256, 0, stream>>>(row_ptr, esrc, h1b, al1sb, al1db, b1, helu_b);

    k_transw2<<<(C1 * DOUT + 255) / 256, 256, 0, stream>>>(W2, W2T);
    k_gemm2<<<(NN * DOUT) / 256, 256, 0, stream>>>(helu_b, W2T, a2s, a2d, h2b, al2sb, al2db);
    k_agg2<<<(NN * DOUT) / 256, 256, 0, stream>>>(row_ptr, esrc, h2b, al2sb, al2db, b2, outp);
}

// Round 3
// 349.319 us; speedup vs baseline: 1.6113x; 1.2902x over previous
//
#include <hip/hip_runtime.h>
#include <hip/hip_bf16.h>

// Problem constants (match reference)
#define NN 50000
#define EE 800000
#define EP (EE + NN)        // edges + self loops = 850000
#define DIN 128
#define HID 32
#define HEADS 8
#define C1 (HEADS * HID)    // 256
#define DOUT 16

typedef __attribute__((ext_vector_type(8))) short short8;   // 8 bf16 (4 VGPRs)
typedef __attribute__((ext_vector_type(4))) float float4v;  // MFMA C/D

__device__ inline unsigned short f2bf(float f) {
    __hip_bfloat16 b = __float2bfloat16(f);
    return *reinterpret_cast<unsigned short*>(&b);
}
__device__ inline float bf2f(unsigned short u) {
    union { unsigned int i; float f; } x;
    x.i = ((unsigned int)u) << 16;
    return x.f;
}

// ---------------------------------------------------------------------------
// CSR build: deg init (self loop = 1), count, scan (3 kernels), scatter
// ---------------------------------------------------------------------------
__global__ void k_initdeg(int* __restrict__ deg) {
    int i = blockIdx.x * 256 + threadIdx.x;
    if (i < NN) deg[i] = 1;   // self loop
}

__global__ void k_countdeg(const int* __restrict__ ei, int* __restrict__ deg) {
    int i = blockIdx.x * 256 + threadIdx.x;
    if (i < EE) atomicAdd(&deg[ei[EE + i]], 1);
}

__global__ void k_scan1(const int* __restrict__ deg, int* __restrict__ row_ptr,
                        int* __restrict__ aux) {
    __shared__ int s[1024];
    int t = threadIdx.x;
    int i = blockIdx.x * 1024 + t;
    int v = (i < NN) ? deg[i] : 0;
    int orig = v;
    s[t] = v;
    for (int off = 1; off < 1024; off <<= 1) {
        __syncthreads();
        int u = (t >= off) ? s[t - off] : 0;
        __syncthreads();
        s[t] += u;
    }
    __syncthreads();
    if (i < NN) row_ptr[i] = s[t] - orig;       // exclusive within block
    if (t == 1023) aux[blockIdx.x] = s[t];      // block total
}

__global__ void k_scan2(int* __restrict__ aux, int nb) {
    if (threadIdx.x == 0 && blockIdx.x == 0) {
        int run = 0;
        for (int b = 0; b < nb; b++) { int v = aux[b]; aux[b] = run; run += v; }
    }
}

__global__ void k_scan3(int* __restrict__ row_ptr, const int* __restrict__ aux,
                        int* __restrict__ wp) {
    int i = blockIdx.x * 256 + threadIdx.x;
    if (i < NN) {
        int v = row_ptr[i] + aux[i >> 10];
        row_ptr[i] = v;
        wp[i] = v;
    }
    if (i == 0) row_ptr[NN] = EP;
}

__global__ void k_scatter(const int* __restrict__ ei, int* __restrict__ wp,
                          int* __restrict__ esrc) {
    int i = blockIdx.x * 256 + threadIdx.x;
    if (i < EE) {
        int s = ei[i];
        int d = ei[EE + i];
        int pos = atomicAdd(&wp[d], 1);
        esrc[pos] = s;
    } else if (i < EP) {
        int n = i - EE;
        int pos = atomicAdd(&wp[n], 1);
        esrc[pos] = n;   // self loop
    }
}

// ---------------------------------------------------------------------------
// GEMM1: h1b[N,256](bf16) = x[N,128] @ W1[128,256]  (fp32 compute, 128x128
// tile, 8x8/thread) + fused al1 attention-logit epilogue.
// ---------------------------------------------------------------------------
__global__ __launch_bounds__(256) void k_gemm1(const float* __restrict__ x,
                                               const float* __restrict__ W1,
                                               const float* __restrict__ a1s,
                                               const float* __restrict__ a1d,
                                               unsigned short* __restrict__ h1b,
                                               float* __restrict__ al1s,
                                               float* __restrict__ al1d) {
    __shared__ float As[32][132];   // [k][node] transposed, padded
    __shared__ float Bs[32][132];   // [k][col], padded
    int tid = threadIdx.x;
    int tx = tid & 15, ty = tid >> 4;
    int nb0 = blockIdx.x * 128;
    int cb0 = blockIdx.y * 128;
    float acc[8][8];
    #pragma unroll
    for (int i = 0; i < 8; i++)
        #pragma unroll
        for (int j = 0; j < 8; j++) acc[i][j] = 0.0f;

    int qa = tid & 7, ra = tid >> 3;          // A loader: k group, node
    int cb_l = (tid & 31) * 4, kr = tid >> 5; // B loader

    for (int kc = 0; kc < 128; kc += 32) {
        #pragma unroll
        for (int p = 0; p < 4; p++) {
            int n_l = p * 32 + ra;
            int node = nb0 + n_l;
            float4 v = make_float4(0.f, 0.f, 0.f, 0.f);
            if (node < NN) v = *(const float4*)(x + node * DIN + kc + qa * 4);
            As[qa * 4 + 0][n_l] = v.x;
            As[qa * 4 + 1][n_l] = v.y;
            As[qa * 4 + 2][n_l] = v.z;
            As[qa * 4 + 3][n_l] = v.w;
        }
        #pragma unroll
        for (int p = 0; p < 4; p++) {
            int k_b = p * 8 + kr;
            float4 v = *(const float4*)(W1 + (kc + k_b) * C1 + cb0 + cb_l);
            *(float4*)&Bs[k_b][cb_l] = v;
        }
        __syncthreads();
        #pragma unroll
        for (int k = 0; k < 32; k++) {
            float4 a0 = *(const float4*)&As[k][ty * 8];
            float4 a1 = *(const float4*)&As[k][ty * 8 + 4];
            float4 b0 = *(const float4*)&Bs[k][tx * 8];
            float4 b1 = *(const float4*)&Bs[k][tx * 8 + 4];
            float a[8] = {a0.x, a0.y, a0.z, a0.w, a1.x, a1.y, a1.z, a1.w};
            float b[8] = {b0.x, b0.y, b0.z, b0.w, b1.x, b1.y, b1.z, b1.w};
            #pragma unroll
            for (int i = 0; i < 8; i++)
                #pragma unroll
                for (int j = 0; j < 8; j++) acc[i][j] += a[i] * b[j];
        }
        __syncthreads();
    }

    // epilogue: bf16 store + fused al1 (head = 32 cols = 4 threads' strips)
    float a_s[8], a_d[8];
    int cg0 = cb0 + tx * 8;
    #pragma unroll
    for (int j = 0; j < 8; j++) {
        a_s[j] = a1s[cg0 + j];
        a_d[j] = a1d[cg0 + j];
    }
    int head = cg0 >> 5;
    #pragma unroll
    for (int i = 0; i < 8; i++) {
        int node = nb0 + ty * 8 + i;
        if (node < NN) {
            uint4 pk;
            pk.x = (unsigned)f2bf(acc[i][0]) | ((unsigned)f2bf(acc[i][1]) << 16);
            pk.y = (unsigned)f2bf(acc[i][2]) | ((unsigned)f2bf(acc[i][3]) << 16);
            pk.z = (unsigned)f2bf(acc[i][4]) | ((unsigned)f2bf(acc[i][5]) << 16);
            pk.w = (unsigned)f2bf(acc[i][6]) | ((unsigned)f2bf(acc[i][7]) << 16);
            *(uint4*)(h1b + node * C1 + cg0) = pk;
        }
        float ps = 0.f, pd = 0.f;
        #pragma unroll
        for (int j = 0; j < 8; j++) {
            ps += acc[i][j] * a_s[j];
            pd += acc[i][j] * a_d[j];
        }
        ps += __shfl_xor(ps, 1, 64); ps += __shfl_xor(ps, 2, 64);
        pd += __shfl_xor(pd, 1, 64); pd += __shfl_xor(pd, 2, 64);
        if ((tx & 3) == 0 && node < NN) {
            al1s[node * 8 + head] = ps;
            al1d[node * 8 + head] = pd;
        }
    }
}

// ---------------------------------------------------------------------------
// agg1: one wave per dst node. lane L: head = L>>3, channels (L&7)*4 .. +3.
// ---------------------------------------------------------------------------
__global__ __launch_bounds__(256) void k_agg1(const int* __restrict__ row_ptr,
                                              const int* __restrict__ esrc,
                                              const unsigned short* __restrict__ h1b,
                                              const float* __restrict__ al1s,
                                              const float* __restrict__ al1d,
                                              const float* __restrict__ b1,
                                              unsigned short* __restrict__ helu_b) {
    int wid = (blockIdx.x * 256 + threadIdx.x) >> 6;
    int L = threadIdx.x & 63;
    if (wid >= NN) return;
    int d = wid;
    int h = L >> 3;
    int start = row_ptr[d], end = row_ptr[d + 1];
    float ald = al1d[d * 8 + h];
    float denom = 0.f;
    float4 acc = make_float4(0.f, 0.f, 0.f, 0.f);
    for (int base = start; base < end; base += 64) {
        int mye = (base + L < end) ? esrc[base + L] : 0;
        int cnt = min(64, end - base);
        for (int i = 0; i < cnt; i++) {
            int s = __shfl(mye, i, 64);
            float v = al1s[s * 8 + h] + ald;
            v = v > 0.f ? v : 0.2f * v;
            float w = __expf(v);
            denom += w;
            uint2 hv = *(const uint2*)(h1b + s * C1 + L * 4);
            acc.x += w * bf2f((unsigned short)(hv.x & 0xffff));
            acc.y += w * bf2f((unsigned short)(hv.x >> 16));
            acc.z += w * bf2f((unsigned short)(hv.y & 0xffff));
            acc.w += w * bf2f((unsigned short)(hv.y >> 16));
        }
    }
    float inv = 1.0f / (denom + 1e-16f);
    float4 bv = *(const float4*)(b1 + L * 4);
    float o0 = acc.x * inv + bv.x;
    float o1 = acc.y * inv + bv.y;
    float o2 = acc.z * inv + bv.z;
    float o3 = acc.w * inv + bv.w;
    o0 = o0 > 0.f ? o0 : __expf(o0) - 1.0f;
    o1 = o1 > 0.f ? o1 : __expf(o1) - 1.0f;
    o2 = o2 > 0.f ? o2 : __expf(o2) - 1.0f;
    o3 = o3 > 0.f ? o3 : __expf(o3) - 1.0f;
    uint2 pk;
    pk.x = (unsigned)f2bf(o0) | ((unsigned)f2bf(o1) << 16);
    pk.y = (unsigned)f2bf(o2) | ((unsigned)f2bf(o3) << 16);
    *(uint2*)(helu_b + d * C1 + L * 4) = pk;
}

// ---------------------------------------------------------------------------
// W2 cast fp32 -> bf16 (4096 elements), keeps [k][c] row-major layout
// ---------------------------------------------------------------------------
__global__ void k_prepw2(const float* __restrict__ W2, unsigned short* __restrict__ W2b) {
    int i = blockIdx.x * 256 + threadIdx.x;
    if (i < C1 * DOUT) W2b[i] = f2bf(W2[i]);
}

// ---------------------------------------------------------------------------
// GEMM2 via MFMA 16x16x32 bf16: one wave = 16 nodes x 16 cols, K=256 in 8
// steps. A-frag: A[m=lane&15][k=quad*8+j] -> one contiguous 16B load/step.
// B-frag: B[k=quad*8+j][n=lane&15] from W2b (preloaded, 8 KB, cached).
// D-layout (m89-verified): col=lane&15, row=quad*4+reg.
// Fused al2_src/al2_dst epilogue via 16-lane quad shuffle reduction.
// ---------------------------------------------------------------------------
__global__ __launch_bounds__(256) void k_gemm2(const unsigned short* __restrict__ helu_b,
                                               const unsigned short* __restrict__ W2b,
                                               const float* __restrict__ a2s,
                                               const float* __restrict__ a2d,
                                               unsigned short* __restrict__ h2b,
                                               float* __restrict__ al2s,
                                               float* __restrict__ al2d) {
    int wid = (blockIdx.x * 256 + threadIdx.x) >> 6;
    int lane = threadIdx.x & 63;
    int nb = wid * 16;          // 50000 = 3125 * 16, exact
    if (nb >= NN) return;
    int m = lane & 15, quad = lane >> 4;

    // B fragments for all 8 K-steps: 64 bf16/lane
    short8 bfrag[8];
    #pragma unroll
    for (int s = 0; s < 8; s++) {
        #pragma unroll
        for (int j = 0; j < 8; j++) {
            ((short*)&bfrag[s])[j] = (short)W2b[(s * 32 + quad * 8 + j) * DOUT + m];
        }
    }

    float4v acc = {0.f, 0.f, 0.f, 0.f};
    const unsigned short* arow = helu_b + (nb + m) * C1 + quad * 8;
    #pragma unroll
    for (int s = 0; s < 8; s++) {
        short8 afrag = *(const short8*)(arow + s * 32);
        acc = __builtin_amdgcn_mfma_f32_16x16x32_bf16(afrag, bfrag[s], acc, 0, 0, 0);
    }

    float as_c = a2s[m], ad_c = a2d[m];
    #pragma unroll
    for (int r = 0; r < 4; r++) {
        int node = nb + quad * 4 + r;
        float val = acc[r];
        h2b[node * DOUT + m] = f2bf(val);
        float ps = val * as_c;
        float pd = val * ad_c;
        ps += __shfl_xor(ps, 1, 64); ps += __shfl_xor(ps, 2, 64);
        ps += __shfl_xor(ps, 4, 64); ps += __shfl_xor(ps, 8, 64);
        pd += __shfl_xor(pd, 1, 64); pd += __shfl_xor(pd, 2, 64);
        pd += __shfl_xor(pd, 4, 64); pd += __shfl_xor(pd, 8, 64);
        if (m == 0) {
            al2s[node] = ps;
            al2d[node] = pd;
        }
    }
}

// ---------------------------------------------------------------------------
// agg2 + bias + log_softmax: 16 lanes per node (4 nodes/wave), bf16 h2 gather
// ---------------------------------------------------------------------------
__global__ __launch_bounds__(256) void k_agg2(const int* __restrict__ row_ptr,
                                              const int* __restrict__ esrc,
                                              const unsigned short* __restrict__ h2b,
                                              const float* __restrict__ al2s,
                                              const float* __restrict__ al2d,
                                              const float* __restrict__ b2,
                                              float* __restrict__ out) {
    int gid = blockIdx.x * 256 + threadIdx.x;
    int n = gid >> 4, c = gid & 15;
    if (n >= NN) return;
    int start = row_ptr[n], end = row_ptr[n + 1];
    float ald = al2d[n];
    float acc = 0.f, denom = 0.f;
    for (int idx = start; idx < end; idx++) {
        int s = esrc[idx];
        float v = al2s[s] + ald;
        v = v > 0.f ? v : 0.2f * v;
        float w = __expf(v);
        denom += w;
        acc += w * bf2f(h2b[s * DOUT + c]);
    }
    float val = acc / (denom + 1e-16f) + b2[c];
    float m = val;
    #pragma unroll
    for (int mm = 1; mm < 16; mm <<= 1) m = fmaxf(m, __shfl_xor(m, mm, 64));
    float ex = __expf(val - m);
    float se = ex;
    #pragma unroll
    for (int mm = 1; mm < 16; mm <<= 1) se += __shfl_xor(se, mm, 64);
    out[n * DOUT + c] = val - m - __logf(se);
}

// ---------------------------------------------------------------------------
extern "C" void kernel_launch(void* const* d_in, const int* in_sizes, int n_in,
                              void* d_out, int out_size, void* d_ws, size_t ws_size,
                              hipStream_t stream) {
    const float* x   = (const float*)d_in[0];
    const int*   ei  = (const int*)d_in[1];
    const float* W1  = (const float*)d_in[2];
    const float* a1s = (const float*)d_in[3];
    const float* a1d = (const float*)d_in[4];
    const float* b1  = (const float*)d_in[5];
    const float* W2  = (const float*)d_in[6];
    const float* a2s = (const float*)d_in[7];
    const float* a2d = (const float*)d_in[8];
    const float* b2  = (const float*)d_in[9];
    float* outp = (float*)d_out;

    // workspace layout
    unsigned short* h1b    = (unsigned short*)d_ws;      // N*256 bf16
    unsigned short* helu_b = h1b + NN * C1;              // N*256 bf16
    unsigned short* h2b    = helu_b + NN * C1;           // N*16 bf16
    unsigned short* W2b    = h2b + NN * DOUT;            // 4096 bf16
    float* al1sb = (float*)(W2b + C1 * DOUT);            // N*8
    float* al1db = al1sb + NN * HEADS;                   // N*8
    float* al2sb = al1db + NN * HEADS;                   // N
    float* al2db = al2sb + NN;                           // N
    int* deg     = (int*)(al2db + NN);                   // N
    int* row_ptr = deg + NN;                             // N+1
    int* wp      = row_ptr + NN + 1;                     // N
    int* esrc    = wp + NN;                              // EP
    int* aux     = esrc + EP;                            // 64

    const int nscan = (NN + 1023) / 1024;   // 49

    k_initdeg<<<(NN + 255) / 256, 256, 0, stream>>>(deg);
    k_countdeg<<<(EE + 255) / 256, 256, 0, stream>>>(ei, deg);
    k_scan1<<<nscan, 1024, 0, stream>>>(deg, row_ptr, aux);
    k_scan2<<<1, 64, 0, stream>>>(aux, nscan);
    k_scan3<<<(NN + 255) / 256, 256, 0, stream>>>(row_ptr, aux, wp);
    k_scatter<<<(EP + 255) / 256, 256, 0, stream>>>(ei, wp, esrc);

    dim3 g1((NN + 127) / 128, 2);
    k_gemm1<<<g1, 256, 0, stream>>>(x, W1, a1s, a1d, h1b, al1sb, al1db);
    k_agg1<<<(NN * 64 + 255) / 256, 256, 0, stream>>>(row_ptr, esrc, h1b, al1sb, al1db, b1, helu_b);

    k_prepw2<<<(C1 * DOUT + 255) / 256, 256, 0, stream>>>(W2, W2b);
    // 3125 waves of 16 nodes each; 4 waves/block -> 782 blocks (tail guarded)
    k_gemm2<<<(3125 * 64 + 255) / 256, 256, 0, stream>>>(helu_b, W2b, a2s, a2d, h2b, al2sb, al2db);
    k_agg2<<<(NN * DOUT) / 256, 256, 0, stream>>>(row_ptr, esrc, h2b, al2sb, al2db, b2, outp);
}

// Round 4
// 346.036 us; speedup vs baseline: 1.6266x; 1.0095x over previous
//
#include <hip/hip_runtime.h>
#include <hip/hip_bf16.h>

// Problem constants (match reference)
#define NN 50000
#define EE 800000
#define EP (EE + NN)        // edges + self loops = 850000
#define DIN 128
#define HID 32
#define HEADS 8
#define C1 (HEADS * HID)    // 256
#define DOUT 16

typedef __attribute__((ext_vector_type(8))) short short8;   // 8 bf16 (4 VGPRs)
typedef __attribute__((ext_vector_type(4))) float float4v;  // MFMA C/D

__device__ inline unsigned short f2bf(float f) {
    __hip_bfloat16 b = __float2bfloat16(f);
    return *reinterpret_cast<unsigned short*>(&b);
}
__device__ inline float bf2f(unsigned short u) {
    union { unsigned int i; float f; } x;
    x.i = ((unsigned int)u) << 16;
    return x.f;
}
__device__ inline float bflo(unsigned u) {   // low bf16 of packed pair -> f32
    union { unsigned int i; float f; } x;
    x.i = u << 16;
    return x.f;
}
__device__ inline float bfhi(unsigned u) {   // high bf16 of packed pair -> f32
    union { unsigned int i; float f; } x;
    x.i = u & 0xffff0000u;
    return x.f;
}

// ---------------------------------------------------------------------------
// CSR build: deg init (self loop = 1), count, scan (3 kernels), scatter
// ---------------------------------------------------------------------------
__global__ void k_initdeg(int* __restrict__ deg) {
    int i = blockIdx.x * 256 + threadIdx.x;
    if (i < NN) deg[i] = 1;   // self loop
}

__global__ void k_countdeg(const int* __restrict__ ei, int* __restrict__ deg) {
    int i = blockIdx.x * 256 + threadIdx.x;
    if (i < EE) atomicAdd(&deg[ei[EE + i]], 1);
}

__global__ void k_scan1(const int* __restrict__ deg, int* __restrict__ row_ptr,
                        int* __restrict__ aux) {
    __shared__ int s[1024];
    int t = threadIdx.x;
    int i = blockIdx.x * 1024 + t;
    int v = (i < NN) ? deg[i] : 0;
    int orig = v;
    s[t] = v;
    for (int off = 1; off < 1024; off <<= 1) {
        __syncthreads();
        int u = (t >= off) ? s[t - off] : 0;
        __syncthreads();
        s[t] += u;
    }
    __syncthreads();
    if (i < NN) row_ptr[i] = s[t] - orig;       // exclusive within block
    if (t == 1023) aux[blockIdx.x] = s[t];      // block total
}

__global__ void k_scan2(int* __restrict__ aux, int nb) {
    if (threadIdx.x == 0 && blockIdx.x == 0) {
        int run = 0;
        for (int b = 0; b < nb; b++) { int v = aux[b]; aux[b] = run; run += v; }
    }
}

__global__ void k_scan3(int* __restrict__ row_ptr, const int* __restrict__ aux,
                        int* __restrict__ wp) {
    int i = blockIdx.x * 256 + threadIdx.x;
    if (i < NN) {
        int v = row_ptr[i] + aux[i >> 10];
        row_ptr[i] = v;
        wp[i] = v;
    }
    if (i == 0) row_ptr[NN] = EP;
}

__global__ void k_scatter(const int* __restrict__ ei, int* __restrict__ wp,
                          int* __restrict__ esrc) {
    int i = blockIdx.x * 256 + threadIdx.x;
    if (i < EE) {
        int s = ei[i];
        int d = ei[EE + i];
        int pos = atomicAdd(&wp[d], 1);
        esrc[pos] = s;
    } else if (i < EP) {
        int n = i - EE;
        int pos = atomicAdd(&wp[n], 1);
        esrc[pos] = n;   // self loop
    }
}

// ---------------------------------------------------------------------------
// GEMM1: h1b[N,256](bf16) = x[N,128] @ W1[128,256]  (fp32 compute, 128x128
// tile, 8x8/thread) + fused al1 attention-logit epilogue.
// ---------------------------------------------------------------------------
__global__ __launch_bounds__(256) void k_gemm1(const float* __restrict__ x,
                                               const float* __restrict__ W1,
                                               const float* __restrict__ a1s,
                                               const float* __restrict__ a1d,
                                               unsigned short* __restrict__ h1b,
                                               float* __restrict__ al1s,
                                               float* __restrict__ al1d) {
    __shared__ float As[32][132];   // [k][node] transposed, padded
    __shared__ float Bs[32][132];   // [k][col], padded
    int tid = threadIdx.x;
    int tx = tid & 15, ty = tid >> 4;
    int nb0 = blockIdx.x * 128;
    int cb0 = blockIdx.y * 128;
    float acc[8][8];
    #pragma unroll
    for (int i = 0; i < 8; i++)
        #pragma unroll
        for (int j = 0; j < 8; j++) acc[i][j] = 0.0f;

    int qa = tid & 7, ra = tid >> 3;          // A loader: k group, node
    int cb_l = (tid & 31) * 4, kr = tid >> 5; // B loader

    for (int kc = 0; kc < 128; kc += 32) {
        #pragma unroll
        for (int p = 0; p < 4; p++) {
            int n_l = p * 32 + ra;
            int node = nb0 + n_l;
            float4 v = make_float4(0.f, 0.f, 0.f, 0.f);
            if (node < NN) v = *(const float4*)(x + node * DIN + kc + qa * 4);
            As[qa * 4 + 0][n_l] = v.x;
            As[qa * 4 + 1][n_l] = v.y;
            As[qa * 4 + 2][n_l] = v.z;
            As[qa * 4 + 3][n_l] = v.w;
        }
        #pragma unroll
        for (int p = 0; p < 4; p++) {
            int k_b = p * 8 + kr;
            float4 v = *(const float4*)(W1 + (kc + k_b) * C1 + cb0 + cb_l);
            *(float4*)&Bs[k_b][cb_l] = v;
        }
        __syncthreads();
        #pragma unroll
        for (int k = 0; k < 32; k++) {
            float4 a0 = *(const float4*)&As[k][ty * 8];
            float4 a1 = *(const float4*)&As[k][ty * 8 + 4];
            float4 b0 = *(const float4*)&Bs[k][tx * 8];
            float4 b1 = *(const float4*)&Bs[k][tx * 8 + 4];
            float a[8] = {a0.x, a0.y, a0.z, a0.w, a1.x, a1.y, a1.z, a1.w};
            float b[8] = {b0.x, b0.y, b0.z, b0.w, b1.x, b1.y, b1.z, b1.w};
            #pragma unroll
            for (int i = 0; i < 8; i++)
                #pragma unroll
                for (int j = 0; j < 8; j++) acc[i][j] += a[i] * b[j];
        }
        __syncthreads();
    }

    // epilogue: bf16 store + fused al1 (head = 32 cols = 4 threads' strips)
    float a_s[8], a_d[8];
    int cg0 = cb0 + tx * 8;
    #pragma unroll
    for (int j = 0; j < 8; j++) {
        a_s[j] = a1s[cg0 + j];
        a_d[j] = a1d[cg0 + j];
    }
    int head = cg0 >> 5;
    #pragma unroll
    for (int i = 0; i < 8; i++) {
        int node = nb0 + ty * 8 + i;
        if (node < NN) {
            uint4 pk;
            pk.x = (unsigned)f2bf(acc[i][0]) | ((unsigned)f2bf(acc[i][1]) << 16);
            pk.y = (unsigned)f2bf(acc[i][2]) | ((unsigned)f2bf(acc[i][3]) << 16);
            pk.z = (unsigned)f2bf(acc[i][4]) | ((unsigned)f2bf(acc[i][5]) << 16);
            pk.w = (unsigned)f2bf(acc[i][6]) | ((unsigned)f2bf(acc[i][7]) << 16);
            *(uint4*)(h1b + node * C1 + cg0) = pk;
        }
        float ps = 0.f, pd = 0.f;
        #pragma unroll
        for (int j = 0; j < 8; j++) {
            ps += acc[i][j] * a_s[j];
            pd += acc[i][j] * a_d[j];
        }
        ps += __shfl_xor(ps, 1, 64); ps += __shfl_xor(ps, 2, 64);
        pd += __shfl_xor(pd, 1, 64); pd += __shfl_xor(pd, 2, 64);
        if ((tx & 3) == 0 && node < NN) {
            al1s[node * 8 + head] = ps;
            al1d[node * 8 + head] = pd;
        }
    }
}

// ---------------------------------------------------------------------------
// agg1: one wave per dst node, two-phase.
// Phase 1 (per 64-edge batch): lane e computes ALL 8 head-weights of edge e
//   (lane-parallel exp, no redundancy) -> wave-private LDS {src, w[8]}.
//   Pad lanes (e >= cnt) write w=0, s=d (valid address, zero contribution).
// Phase 2: gather loop unrolled x4 -- 4 independent 512B row-gathers in
//   flight per wave. lane L: head L>>3, channels (L&7)*4..+3.
// No __syncthreads: LDS is wave-private (waves have divergent trip counts).
// ---------------------------------------------------------------------------
__global__ __launch_bounds__(256) void k_agg1(const int* __restrict__ row_ptr,
                                              const int* __restrict__ esrc,
                                              const unsigned short* __restrict__ h1b,
                                              const float* __restrict__ al1s,
                                              const float* __restrict__ al1d,
                                              const float* __restrict__ b1,
                                              unsigned short* __restrict__ helu_b) {
    __shared__ float wbuf[4][64 * 8];
    __shared__ int   sbuf[4][64];
    int wslot = threadIdx.x >> 6;
    int L = threadIdx.x & 63;
    int d = (blockIdx.x * 256 + threadIdx.x) >> 6;
    if (d >= NN) return;
    int h = L >> 3;
    int start = row_ptr[d], end = row_ptr[d + 1];
    float4 ald0 = *(const float4*)(al1d + d * 8);
    float4 ald1 = *(const float4*)(al1d + d * 8 + 4);
    float* wrow = wbuf[wslot];
    int* srow = sbuf[wslot];
    float denom = 0.f;
    float4 acc = make_float4(0.f, 0.f, 0.f, 0.f);
    const int Lofs = L * 4;

    for (int base = start; base < end; base += 64) {
        int cnt = min(64, end - base);
        // ---- phase 1: lane-parallel weights ----
        int s = d;
        float wv0 = 0.f, wv1 = 0.f, wv2 = 0.f, wv3 = 0.f;
        float wv4 = 0.f, wv5 = 0.f, wv6 = 0.f, wv7 = 0.f;
        if (L < cnt) {
            s = esrc[base + L];
            float4 as0 = *(const float4*)(al1s + s * 8);
            float4 as1 = *(const float4*)(al1s + s * 8 + 4);
            float e;
            e = as0.x + ald0.x; e = e > 0.f ? e : 0.2f * e; wv0 = __expf(e);
            e = as0.y + ald0.y; e = e > 0.f ? e : 0.2f * e; wv1 = __expf(e);
            e = as0.z + ald0.z; e = e > 0.f ? e : 0.2f * e; wv2 = __expf(e);
            e = as0.w + ald0.w; e = e > 0.f ? e : 0.2f * e; wv3 = __expf(e);
            e = as1.x + ald1.x; e = e > 0.f ? e : 0.2f * e; wv4 = __expf(e);
            e = as1.y + ald1.y; e = e > 0.f ? e : 0.2f * e; wv5 = __expf(e);
            e = as1.z + ald1.z; e = e > 0.f ? e : 0.2f * e; wv6 = __expf(e);
            e = as1.w + ald1.w; e = e > 0.f ? e : 0.2f * e; wv7 = __expf(e);
        }
        srow[L] = s;
        *(float4*)&wrow[L * 8]     = make_float4(wv0, wv1, wv2, wv3);
        *(float4*)&wrow[L * 8 + 4] = make_float4(wv4, wv5, wv6, wv7);
        // ---- phase 2: gather, unrolled x4 ----
        int cnt4 = (cnt + 3) & ~3;
        for (int i = 0; i < cnt4; i += 4) {
            int s0 = srow[i], s1 = srow[i + 1], s2 = srow[i + 2], s3 = srow[i + 3];
            float x0 = wrow[i * 8 + h];
            float x1 = wrow[i * 8 + 8 + h];
            float x2 = wrow[i * 8 + 16 + h];
            float x3 = wrow[i * 8 + 24 + h];
            uint2 v0 = *(const uint2*)(h1b + s0 * C1 + Lofs);
            uint2 v1 = *(const uint2*)(h1b + s1 * C1 + Lofs);
            uint2 v2 = *(const uint2*)(h1b + s2 * C1 + Lofs);
            uint2 v3 = *(const uint2*)(h1b + s3 * C1 + Lofs);
            denom += (x0 + x1) + (x2 + x3);
            acc.x += x0 * bflo(v0.x); acc.y += x0 * bfhi(v0.x);
            acc.z += x0 * bflo(v0.y); acc.w += x0 * bfhi(v0.y);
            acc.x += x1 * bflo(v1.x); acc.y += x1 * bfhi(v1.x);
            acc.z += x1 * bflo(v1.y); acc.w += x1 * bfhi(v1.y);
            acc.x += x2 * bflo(v2.x); acc.y += x2 * bfhi(v2.x);
            acc.z += x2 * bflo(v2.y); acc.w += x2 * bfhi(v2.y);
            acc.x += x3 * bflo(v3.x); acc.y += x3 * bfhi(v3.x);
            acc.z += x3 * bflo(v3.y); acc.w += x3 * bfhi(v3.y);
        }
    }
    float inv = 1.0f / (denom + 1e-16f);
    float4 bv = *(const float4*)(b1 + Lofs);
    float o0 = acc.x * inv + bv.x;
    float o1 = acc.y * inv + bv.y;
    float o2 = acc.z * inv + bv.z;
    float o3 = acc.w * inv + bv.w;
    o0 = o0 > 0.f ? o0 : __expf(o0) - 1.0f;
    o1 = o1 > 0.f ? o1 : __expf(o1) - 1.0f;
    o2 = o2 > 0.f ? o2 : __expf(o2) - 1.0f;
    o3 = o3 > 0.f ? o3 : __expf(o3) - 1.0f;
    uint2 pk;
    pk.x = (unsigned)f2bf(o0) | ((unsigned)f2bf(o1) << 16);
    pk.y = (unsigned)f2bf(o2) | ((unsigned)f2bf(o3) << 16);
    *(uint2*)(helu_b + d * C1 + Lofs) = pk;
}

// ---------------------------------------------------------------------------
// W2 cast fp32 -> bf16 (4096 elements), keeps [k][c] row-major layout
// ---------------------------------------------------------------------------
__global__ void k_prepw2(const float* __restrict__ W2, unsigned short* __restrict__ W2b) {
    int i = blockIdx.x * 256 + threadIdx.x;
    if (i < C1 * DOUT) W2b[i] = f2bf(W2[i]);
}

// ---------------------------------------------------------------------------
// GEMM2 via MFMA 16x16x32 bf16 + fused al2 epilogue (unchanged from R3).
// ---------------------------------------------------------------------------
__global__ __launch_bounds__(256) void k_gemm2(const unsigned short* __restrict__ helu_b,
                                               const unsigned short* __restrict__ W2b,
                                               const float* __restrict__ a2s,
                                               const float* __restrict__ a2d,
                                               unsigned short* __restrict__ h2b,
                                               float* __restrict__ al2s,
                                               float* __restrict__ al2d) {
    int wid = (blockIdx.x * 256 + threadIdx.x) >> 6;
    int lane = threadIdx.x & 63;
    int nb = wid * 16;          // 50000 = 3125 * 16, exact
    if (nb >= NN) return;
    int m = lane & 15, quad = lane >> 4;

    short8 bfrag[8];
    #pragma unroll
    for (int s = 0; s < 8; s++) {
        #pragma unroll
        for (int j = 0; j < 8; j++) {
            ((short*)&bfrag[s])[j] = (short)W2b[(s * 32 + quad * 8 + j) * DOUT + m];
        }
    }

    float4v acc = {0.f, 0.f, 0.f, 0.f};
    const unsigned short* arow = helu_b + (nb + m) * C1 + quad * 8;
    #pragma unroll
    for (int s = 0; s < 8; s++) {
        short8 afrag = *(const short8*)(arow + s * 32);
        acc = __builtin_amdgcn_mfma_f32_16x16x32_bf16(afrag, bfrag[s], acc, 0, 0, 0);
    }

    float as_c = a2s[m], ad_c = a2d[m];
    #pragma unroll
    for (int r = 0; r < 4; r++) {
        int node = nb + quad * 4 + r;
        float val = acc[r];
        h2b[node * DOUT + m] = f2bf(val);
        float ps = val * as_c;
        float pd = val * ad_c;
        ps += __shfl_xor(ps, 1, 64); ps += __shfl_xor(ps, 2, 64);
        ps += __shfl_xor(ps, 4, 64); ps += __shfl_xor(ps, 8, 64);
        pd += __shfl_xor(pd, 1, 64); pd += __shfl_xor(pd, 2, 64);
        pd += __shfl_xor(pd, 4, 64); pd += __shfl_xor(pd, 8, 64);
        if (m == 0) {
            al2s[node] = ps;
            al2d[node] = pd;
        }
    }
}

// ---------------------------------------------------------------------------
// agg2 + bias + log_softmax: one wave per node, two-phase.
// Phase 1: lane e computes weight of edge e (lane-parallel exp).
// Phase 2: lanes split as 4 edge-slots x 16 channels (g = L>>4, c = L&15);
// group partials reduced via shfl_xor(16/32). No block barrier (wave-private
// LDS, divergent trip counts).
// ---------------------------------------------------------------------------
__global__ __launch_bounds__(256) void k_agg2(const int* __restrict__ row_ptr,
                                              const int* __restrict__ esrc,
                                              const unsigned short* __restrict__ h2b,
                                              const float* __restrict__ al2s,
                                              const float* __restrict__ al2d,
                                              const float* __restrict__ b2,
                                              float* __restrict__ out) {
    __shared__ float wbuf2[4][64];
    __shared__ int   sbuf2[4][64];
    int wslot = threadIdx.x >> 6;
    int L = threadIdx.x & 63;
    int n = (blockIdx.x * 256 + threadIdx.x) >> 6;
    if (n >= NN) return;
    int c = L & 15, g = L >> 4;
    int start = row_ptr[n], end = row_ptr[n + 1];
    float ald = al2d[n];
    float* wrow = wbuf2[wslot];
    int* srow = sbuf2[wslot];
    float acc = 0.f, denom = 0.f;

    for (int base = start; base < end; base += 64) {
        int cnt = min(64, end - base);
        int s = n; float w = 0.f;
        if (L < cnt) {
            s = esrc[base + L];
            float e = al2s[s] + ald;
            e = e > 0.f ? e : 0.2f * e;
            w = __expf(e);
        }
        srow[L] = s;
        wrow[L] = w;
        int cnt4 = (cnt + 3) & ~3;
        for (int i = 0; i < cnt4; i += 4) {
            int idx = i + g;
            int ss = srow[idx];
            float ww = wrow[idx];
            float v = bf2f(h2b[ss * DOUT + c]);
            acc += ww * v;
            denom += ww;
        }
    }
    // reduce the 4 edge-slot groups (xor flips g bits, keeps c)
    acc += __shfl_xor(acc, 16, 64);   acc += __shfl_xor(acc, 32, 64);
    denom += __shfl_xor(denom, 16, 64); denom += __shfl_xor(denom, 32, 64);
    float val = acc / (denom + 1e-16f) + b2[c];
    // log_softmax over 16 channels
    float m = val;
    #pragma unroll
    for (int mm = 1; mm < 16; mm <<= 1) m = fmaxf(m, __shfl_xor(m, mm, 64));
    float ex = __expf(val - m);
    float se = ex;
    #pragma unroll
    for (int mm = 1; mm < 16; mm <<= 1) se += __shfl_xor(se, mm, 64);
    if (L < 16) out[n * DOUT + c] = val - m - __logf(se);
}

// ---------------------------------------------------------------------------
extern "C" void kernel_launch(void* const* d_in, const int* in_sizes, int n_in,
                              void* d_out, int out_size, void* d_ws, size_t ws_size,
                              hipStream_t stream) {
    const float* x   = (const float*)d_in[0];
    const int*   ei  = (const int*)d_in[1];
    const float* W1  = (const float*)d_in[2];
    const float* a1s = (const float*)d_in[3];
    const float* a1d = (const float*)d_in[4];
    const float* b1  = (const float*)d_in[5];
    const float* W2  = (const float*)d_in[6];
    const float* a2s = (const float*)d_in[7];
    const float* a2d = (const float*)d_in[8];
    const float* b2  = (const float*)d_in[9];
    float* outp = (float*)d_out;

    // workspace layout
    unsigned short* h1b    = (unsigned short*)d_ws;      // N*256 bf16
    unsigned short* helu_b = h1b + NN * C1;              // N*256 bf16
    unsigned short* h2b    = helu_b + NN * C1;           // N*16 bf16
    unsigned short* W2b    = h2b + NN * DOUT;            // 4096 bf16
    float* al1sb = (float*)(W2b + C1 * DOUT);            // N*8
    float* al1db = al1sb + NN * HEADS;                   // N*8
    float* al2sb = al1db + NN * HEADS;                   // N
    float* al2db = al2sb + NN;                           // N
    int* deg     = (int*)(al2db + NN);                   // N
    int* row_ptr = deg + NN;                             // N+1
    int* wp      = row_ptr + NN + 1;                     // N
    int* esrc    = wp + NN;                              // EP
    int* aux     = esrc + EP;                            // 64

    const int nscan = (NN + 1023) / 1024;   // 49

    k_initdeg<<<(NN + 255) / 256, 256, 0, stream>>>(deg);
    k_countdeg<<<(EE + 255) / 256, 256, 0, stream>>>(ei, deg);
    k_scan1<<<nscan, 1024, 0, stream>>>(deg, row_ptr, aux);
    k_scan2<<<1, 64, 0, stream>>>(aux, nscan);
    k_scan3<<<(NN + 255) / 256, 256, 0, stream>>>(row_ptr, aux, wp);
    k_scatter<<<(EP + 255) / 256, 256, 0, stream>>>(ei, wp, esrc);

    dim3 g1((NN + 127) / 128, 2);
    k_gemm1<<<g1, 256, 0, stream>>>(x, W1, a1s, a1d, h1b, al1sb, al1db);
    k_agg1<<<(NN * 64 + 255) / 256, 256, 0, stream>>>(row_ptr, esrc, h1b, al1sb, al1db, b1, helu_b);

    k_prepw2<<<(C1 * DOUT + 255) / 256, 256, 0, stream>>>(W2, W2b);
    k_gemm2<<<(3125 * 64 + 255) / 256, 256, 0, stream>>>(helu_b, W2b, a2s, a2d, h2b, al2sb, al2db);
    k_agg2<<<(NN * 64 + 255) / 256, 256, 0, stream>>>(row_ptr, esrc, h2b, al2sb, al2db, b2, outp);
}

// Round 5
// 333.496 us; speedup vs baseline: 1.6878x; 1.0376x over previous
//
#include <hip/hip_runtime.h>
#include <hip/hip_bf16.h>

// Problem constants (match reference)
#define NN 50000
#define EE 800000
#define EP (EE + NN)        // edges + self loops = 850000
#define DIN 128
#define HID 32
#define HEADS 8
#define C1 (HEADS * HID)    // 256
#define DOUT 16
#define NW1 3125            // gemm1/gemm2 waves: 50000/16

typedef __attribute__((ext_vector_type(8))) short short8;   // 8 bf16 (4 VGPRs)
typedef __attribute__((ext_vector_type(4))) float float4v;  // MFMA C/D

__device__ inline unsigned short f2bf(float f) {
    __hip_bfloat16 b = __float2bfloat16(f);
    return *reinterpret_cast<unsigned short*>(&b);
}
__device__ inline float bf2f(unsigned short u) {
    union { unsigned int i; float f; } x;
    x.i = ((unsigned int)u) << 16;
    return x.f;
}
__device__ inline float bflo(unsigned u) {
    union { unsigned int i; float f; } x;
    x.i = u << 16;
    return x.f;
}
__device__ inline float bfhi(unsigned u) {
    union { unsigned int i; float f; } x;
    x.i = u & 0xffff0000u;
    return x.f;
}

// ---------------------------------------------------------------------------
// CSR build: deg init (self loop = 1), count, scan (3 kernels), scatter
// ---------------------------------------------------------------------------
__global__ void k_initdeg(int* __restrict__ deg) {
    int i = blockIdx.x * 256 + threadIdx.x;
    if (i < NN) deg[i] = 1;   // self loop
}

__global__ void k_countdeg(const int* __restrict__ ei, int* __restrict__ deg) {
    int i = blockIdx.x * 256 + threadIdx.x;
    if (i < EE) atomicAdd(&deg[ei[EE + i]], 1);
}

__global__ void k_scan1(const int* __restrict__ deg, int* __restrict__ row_ptr,
                        int* __restrict__ aux) {
    __shared__ int s[1024];
    int t = threadIdx.x;
    int i = blockIdx.x * 1024 + t;
    int v = (i < NN) ? deg[i] : 0;
    int orig = v;
    s[t] = v;
    for (int off = 1; off < 1024; off <<= 1) {
        __syncthreads();
        int u = (t >= off) ? s[t - off] : 0;
        __syncthreads();
        s[t] += u;
    }
    __syncthreads();
    if (i < NN) row_ptr[i] = s[t] - orig;       // exclusive within block
    if (t == 1023) aux[blockIdx.x] = s[t];      // block total
}

__global__ void k_scan2(int* __restrict__ aux, int nb) {
    if (threadIdx.x == 0 && blockIdx.x == 0) {
        int run = 0;
        for (int b = 0; b < nb; b++) { int v = aux[b]; aux[b] = run; run += v; }
    }
}

__global__ void k_scan3(int* __restrict__ row_ptr, const int* __restrict__ aux,
                        int* __restrict__ wp) {
    int i = blockIdx.x * 256 + threadIdx.x;
    if (i < NN) {
        int v = row_ptr[i] + aux[i >> 10];
        row_ptr[i] = v;
        wp[i] = v;
    }
    if (i == 0) row_ptr[NN] = EP;
}

__global__ void k_scatter(const int* __restrict__ ei, int* __restrict__ wp,
                          int* __restrict__ esrc) {
    int i = blockIdx.x * 256 + threadIdx.x;
    if (i < EE) {
        int s = ei[i];
        int d = ei[EE + i];
        int pos = atomicAdd(&wp[d], 1);
        esrc[pos] = s;
    } else if (i < EP) {
        int n = i - EE;
        int pos = atomicAdd(&wp[n], 1);
        esrc[pos] = n;   // self loop
    }
}

// ---------------------------------------------------------------------------
// prep: va[k][i] (i<8: src-head i, i>=8: dst-head i-8) = per-head compressed
// attention vectors so al1 = x @ va comes out of the same MFMA as h1.
// ---------------------------------------------------------------------------
__global__ void k_prepva(const float* __restrict__ W1, const float* __restrict__ a1s,
                         const float* __restrict__ a1d, float* __restrict__ va) {
    int i = blockIdx.x * 256 + threadIdx.x;   // 128*16
    if (i >= DIN * 16) return;
    int k = i >> 4, idx = i & 15;
    int h = idx & 7;
    const float* av = (idx < 8) ? a1s : a1d;
    float s = 0.f;
    #pragma unroll
    for (int j = 0; j < 32; j++) s += W1[k * C1 + h * 32 + j] * av[h * 32 + j];
    va[i] = s;
}

// ---------------------------------------------------------------------------
// prep: swizzled bf16 A-fragment image for gemm1.
// 17 col-tiles (16 of W1^T + 1 of va) x 4 K-steps x 64 lanes x 8 bf16.
// A[m=lane&15][k=quad*8+j]; tile c<16: col = c*16+m from W1; c==16: va[k][m].
// ---------------------------------------------------------------------------
__global__ void k_prepfrag(const float* __restrict__ W1, const float* __restrict__ va,
                           unsigned short* __restrict__ w1frag) {
    int i = blockIdx.x * 256 + threadIdx.x;   // 17*4*64*8 = 34816
    if (i >= 17 * 2048) return;
    int j = i & 7, lane = (i >> 3) & 63, s = (i >> 9) & 3, c = i >> 11;
    int q = lane >> 4, m = lane & 15;
    int k = s * 32 + q * 8 + j;
    float val = (c < 16) ? W1[k * C1 + c * 16 + m] : va[k * 16 + m];
    w1frag[i] = f2bf(val);
}

// ---------------------------------------------------------------------------
// GEMM1 via MFMA 16x16x32 bf16, operands swapped: A = W1^T frags (global,
// L2-broadcast), B = x rows (fp32->bf16 in-register). One wave = 16 nodes x
// all 256 cols + the 16 attention logits (17th tile). D-layout: lane holds
// node nb+(lane&15), cols c*16+quad*4+r -> uint2 packed stores, al1 as one
// float4 into al1sd[node][16] (rows 0-7 = src logits, 8-15 = dst logits).
// ---------------------------------------------------------------------------
__global__ __launch_bounds__(256) void k_gemm1(const float* __restrict__ x,
                                               const unsigned short* __restrict__ w1frag,
                                               unsigned short* __restrict__ h1b,
                                               float* __restrict__ al1sd) {
    int wid = (blockIdx.x * 256 + threadIdx.x) >> 6;
    int lane = threadIdx.x & 63;
    if (wid >= NW1) return;
    int nb = wid * 16;
    int m = lane & 15, quad = lane >> 4;
    const float* xrow = x + (nb + m) * DIN;

    float4v acc[17];
    #pragma unroll
    for (int c = 0; c < 17; c++) acc[c] = (float4v){0.f, 0.f, 0.f, 0.f};

    #pragma unroll
    for (int s = 0; s < 4; s++) {
        float4 f0 = *(const float4*)(xrow + s * 32 + quad * 8);
        float4 f1 = *(const float4*)(xrow + s * 32 + quad * 8 + 4);
        short8 bfrag;
        unsigned short* bp = (unsigned short*)&bfrag;
        bp[0] = f2bf(f0.x); bp[1] = f2bf(f0.y); bp[2] = f2bf(f0.z); bp[3] = f2bf(f0.w);
        bp[4] = f2bf(f1.x); bp[5] = f2bf(f1.y); bp[6] = f2bf(f1.z); bp[7] = f2bf(f1.w);
        const unsigned short* fp = w1frag + (s * 64 + lane) * 8;
        #pragma unroll
        for (int c = 0; c < 17; c++) {
            short8 afrag = *(const short8*)(fp + c * 2048);
            acc[c] = __builtin_amdgcn_mfma_f32_16x16x32_bf16(afrag, bfrag, acc[c], 0, 0, 0);
        }
    }

    unsigned short* hrow = h1b + (nb + m) * C1 + quad * 4;
    #pragma unroll
    for (int c = 0; c < 16; c++) {
        uint2 pk;
        pk.x = (unsigned)f2bf(acc[c][0]) | ((unsigned)f2bf(acc[c][1]) << 16);
        pk.y = (unsigned)f2bf(acc[c][2]) | ((unsigned)f2bf(acc[c][3]) << 16);
        *(uint2*)(hrow + c * 16) = pk;
    }
    *(float4*)(al1sd + (nb + m) * 16 + quad * 4) =
        make_float4(acc[16][0], acc[16][1], acc[16][2], acc[16][3]);
}

// ---------------------------------------------------------------------------
// agg1: one wave per dst node, two-phase (R4 structure, al1sd layout).
// ---------------------------------------------------------------------------
__global__ __launch_bounds__(256) void k_agg1(const int* __restrict__ row_ptr,
                                              const int* __restrict__ esrc,
                                              const unsigned short* __restrict__ h1b,
                                              const float* __restrict__ al1sd,
                                              const float* __restrict__ b1,
                                              unsigned short* __restrict__ helu_b) {
    __shared__ float wbuf[4][64 * 8];
    __shared__ int   sbuf[4][64];
    int wslot = threadIdx.x >> 6;
    int L = threadIdx.x & 63;
    int d = (blockIdx.x * 256 + threadIdx.x) >> 6;
    if (d >= NN) return;
    int h = L >> 3;
    int start = row_ptr[d], end = row_ptr[d + 1];
    float4 ald0 = *(const float4*)(al1sd + d * 16 + 8);
    float4 ald1 = *(const float4*)(al1sd + d * 16 + 12);
    float* wrow = wbuf[wslot];
    int* srow = sbuf[wslot];
    float denom = 0.f;
    float4 acc = make_float4(0.f, 0.f, 0.f, 0.f);
    const int Lofs = L * 4;

    for (int base = start; base < end; base += 64) {
        int cnt = min(64, end - base);
        int s = d;
        float wv0 = 0.f, wv1 = 0.f, wv2 = 0.f, wv3 = 0.f;
        float wv4 = 0.f, wv5 = 0.f, wv6 = 0.f, wv7 = 0.f;
        if (L < cnt) {
            s = esrc[base + L];
            float4 as0 = *(const float4*)(al1sd + s * 16);
            float4 as1 = *(const float4*)(al1sd + s * 16 + 4);
            float e;
            e = as0.x + ald0.x; e = e > 0.f ? e : 0.2f * e; wv0 = __expf(e);
            e = as0.y + ald0.y; e = e > 0.f ? e : 0.2f * e; wv1 = __expf(e);
            e = as0.z + ald0.z; e = e > 0.f ? e : 0.2f * e; wv2 = __expf(e);
            e = as0.w + ald0.w; e = e > 0.f ? e : 0.2f * e; wv3 = __expf(e);
            e = as1.x + ald1.x; e = e > 0.f ? e : 0.2f * e; wv4 = __expf(e);
            e = as1.y + ald1.y; e = e > 0.f ? e : 0.2f * e; wv5 = __expf(e);
            e = as1.z + ald1.z; e = e > 0.f ? e : 0.2f * e; wv6 = __expf(e);
            e = as1.w + ald1.w; e = e > 0.f ? e : 0.2f * e; wv7 = __expf(e);
        }
        srow[L] = s;
        *(float4*)&wrow[L * 8]     = make_float4(wv0, wv1, wv2, wv3);
        *(float4*)&wrow[L * 8 + 4] = make_float4(wv4, wv5, wv6, wv7);
        int cnt4 = (cnt + 3) & ~3;
        for (int i = 0; i < cnt4; i += 4) {
            int s0 = srow[i], s1 = srow[i + 1], s2 = srow[i + 2], s3 = srow[i + 3];
            float x0 = wrow[i * 8 + h];
            float x1 = wrow[i * 8 + 8 + h];
            float x2 = wrow[i * 8 + 16 + h];
            float x3 = wrow[i * 8 + 24 + h];
            uint2 v0 = *(const uint2*)(h1b + s0 * C1 + Lofs);
            uint2 v1 = *(const uint2*)(h1b + s1 * C1 + Lofs);
            uint2 v2 = *(const uint2*)(h1b + s2 * C1 + Lofs);
            uint2 v3 = *(const uint2*)(h1b + s3 * C1 + Lofs);
            denom += (x0 + x1) + (x2 + x3);
            acc.x += x0 * bflo(v0.x); acc.y += x0 * bfhi(v0.x);
            acc.z += x0 * bflo(v0.y); acc.w += x0 * bfhi(v0.y);
            acc.x += x1 * bflo(v1.x); acc.y += x1 * bfhi(v1.x);
            acc.z += x1 * bflo(v1.y); acc.w += x1 * bfhi(v1.y);
            acc.x += x2 * bflo(v2.x); acc.y += x2 * bfhi(v2.x);
            acc.z += x2 * bflo(v2.y); acc.w += x2 * bfhi(v2.y);
            acc.x += x3 * bflo(v3.x); acc.y += x3 * bfhi(v3.x);
            acc.z += x3 * bflo(v3.y); acc.w += x3 * bfhi(v3.y);
        }
    }
    float inv = 1.0f / (denom + 1e-16f);
    float4 bv = *(const float4*)(b1 + Lofs);
    float o0 = acc.x * inv + bv.x;
    float o1 = acc.y * inv + bv.y;
    float o2 = acc.z * inv + bv.z;
    float o3 = acc.w * inv + bv.w;
    o0 = o0 > 0.f ? o0 : __expf(o0) - 1.0f;
    o1 = o1 > 0.f ? o1 : __expf(o1) - 1.0f;
    o2 = o2 > 0.f ? o2 : __expf(o2) - 1.0f;
    o3 = o3 > 0.f ? o3 : __expf(o3) - 1.0f;
    uint2 pk;
    pk.x = (unsigned)f2bf(o0) | ((unsigned)f2bf(o1) << 16);
    pk.y = (unsigned)f2bf(o2) | ((unsigned)f2bf(o3) << 16);
    *(uint2*)(helu_b + d * C1 + Lofs) = pk;
}

// ---------------------------------------------------------------------------
// W2 cast fp32 -> bf16 (4096 elements), keeps [k][c] row-major layout
// ---------------------------------------------------------------------------
__global__ void k_prepw2(const float* __restrict__ W2, unsigned short* __restrict__ W2b) {
    int i = blockIdx.x * 256 + threadIdx.x;
    if (i < C1 * DOUT) W2b[i] = f2bf(W2[i]);
}

// ---------------------------------------------------------------------------
// GEMM2 via MFMA 16x16x32 bf16 + fused al2 epilogue (unchanged from R3).
// ---------------------------------------------------------------------------
__global__ __launch_bounds__(256) void k_gemm2(const unsigned short* __restrict__ helu_b,
                                               const unsigned short* __restrict__ W2b,
                                               const float* __restrict__ a2s,
                                               const float* __restrict__ a2d,
                                               unsigned short* __restrict__ h2b,
                                               float* __restrict__ al2s,
                                               float* __restrict__ al2d) {
    int wid = (blockIdx.x * 256 + threadIdx.x) >> 6;
    int lane = threadIdx.x & 63;
    int nb = wid * 16;
    if (nb >= NN) return;
    int m = lane & 15, quad = lane >> 4;

    short8 bfrag[8];
    #pragma unroll
    for (int s = 0; s < 8; s++) {
        #pragma unroll
        for (int j = 0; j < 8; j++) {
            ((short*)&bfrag[s])[j] = (short)W2b[(s * 32 + quad * 8 + j) * DOUT + m];
        }
    }

    float4v acc = {0.f, 0.f, 0.f, 0.f};
    const unsigned short* arow = helu_b + (nb + m) * C1 + quad * 8;
    #pragma unroll
    for (int s = 0; s < 8; s++) {
        short8 afrag = *(const short8*)(arow + s * 32);
        acc = __builtin_amdgcn_mfma_f32_16x16x32_bf16(afrag, bfrag[s], acc, 0, 0, 0);
    }

    float as_c = a2s[m], ad_c = a2d[m];
    #pragma unroll
    for (int r = 0; r < 4; r++) {
        int node = nb + quad * 4 + r;
        float val = acc[r];
        h2b[node * DOUT + m] = f2bf(val);
        float ps = val * as_c;
        float pd = val * ad_c;
        ps += __shfl_xor(ps, 1, 64); ps += __shfl_xor(ps, 2, 64);
        ps += __shfl_xor(ps, 4, 64); ps += __shfl_xor(ps, 8, 64);
        pd += __shfl_xor(pd, 1, 64); pd += __shfl_xor(pd, 2, 64);
        pd += __shfl_xor(pd, 4, 64); pd += __shfl_xor(pd, 8, 64);
        if (m == 0) {
            al2s[node] = ps;
            al2d[node] = pd;
        }
    }
}

// ---------------------------------------------------------------------------
// agg2 + bias + log_softmax: one wave per node, two-phase (unchanged R4).
// ---------------------------------------------------------------------------
__global__ __launch_bounds__(256) void k_agg2(const int* __restrict__ row_ptr,
                                              const int* __restrict__ esrc,
                                              const unsigned short* __restrict__ h2b,
                                              const float* __restrict__ al2s,
                                              const float* __restrict__ al2d,
                                              const float* __restrict__ b2,
                                              float* __restrict__ out) {
    __shared__ float wbuf2[4][64];
    __shared__ int   sbuf2[4][64];
    int wslot = threadIdx.x >> 6;
    int L = threadIdx.x & 63;
    int n = (blockIdx.x * 256 + threadIdx.x) >> 6;
    if (n >= NN) return;
    int c = L & 15, g = L >> 4;
    int start = row_ptr[n], end = row_ptr[n + 1];
    float ald = al2d[n];
    float* wrow = wbuf2[wslot];
    int* srow = sbuf2[wslot];
    float acc = 0.f, denom = 0.f;

    for (int base = start; base < end; base += 64) {
        int cnt = min(64, end - base);
        int s = n; float w = 0.f;
        if (L < cnt) {
            s = esrc[base + L];
            float e = al2s[s] + ald;
            e = e > 0.f ? e : 0.2f * e;
            w = __expf(e);
        }
        srow[L] = s;
        wrow[L] = w;
        int cnt4 = (cnt + 3) & ~3;
        for (int i = 0; i < cnt4; i += 4) {
            int idx = i + g;
            int ss = srow[idx];
            float ww = wrow[idx];
            float v = bf2f(h2b[ss * DOUT + c]);
            acc += ww * v;
            denom += ww;
        }
    }
    acc += __shfl_xor(acc, 16, 64);   acc += __shfl_xor(acc, 32, 64);
    denom += __shfl_xor(denom, 16, 64); denom += __shfl_xor(denom, 32, 64);
    float val = acc / (denom + 1e-16f) + b2[c];
    float m = val;
    #pragma unroll
    for (int mm = 1; mm < 16; mm <<= 1) m = fmaxf(m, __shfl_xor(m, mm, 64));
    float ex = __expf(val - m);
    float se = ex;
    #pragma unroll
    for (int mm = 1; mm < 16; mm <<= 1) se += __shfl_xor(se, mm, 64);
    if (L < 16) out[n * DOUT + c] = val - m - __logf(se);
}

// ---------------------------------------------------------------------------
extern "C" void kernel_launch(void* const* d_in, const int* in_sizes, int n_in,
                              void* d_out, int out_size, void* d_ws, size_t ws_size,
                              hipStream_t stream) {
    const float* x   = (const float*)d_in[0];
    const int*   ei  = (const int*)d_in[1];
    const float* W1  = (const float*)d_in[2];
    const float* a1s = (const float*)d_in[3];
    const float* a1d = (const float*)d_in[4];
    const float* b1  = (const float*)d_in[5];
    const float* W2  = (const float*)d_in[6];
    const float* a2s = (const float*)d_in[7];
    const float* a2d = (const float*)d_in[8];
    const float* b2  = (const float*)d_in[9];
    float* outp = (float*)d_out;

    // workspace layout
    unsigned short* h1b    = (unsigned short*)d_ws;      // N*256 bf16
    unsigned short* helu_b = h1b + NN * C1;              // N*256 bf16
    unsigned short* h2b    = helu_b + NN * C1;           // N*16 bf16
    unsigned short* W2b    = h2b + NN * DOUT;            // 4096 bf16
    unsigned short* w1frag = W2b + C1 * DOUT;            // 34816 bf16
    float* va    = (float*)(w1frag + 17 * 2048);         // 2048
    float* al1sd = va + DIN * 16;                        // N*16
    float* al2sb = al1sd + NN * 16;                      // N
    float* al2db = al2sb + NN;                           // N
    int* deg     = (int*)(al2db + NN);                   // N
    int* row_ptr = deg + NN;                             // N+1
    int* wp      = row_ptr + NN + 1;                     // N
    int* esrc    = wp + NN;                              // EP
    int* aux     = esrc + EP;                            // 64

    const int nscan = (NN + 1023) / 1024;   // 49

    k_initdeg<<<(NN + 255) / 256, 256, 0, stream>>>(deg);
    k_countdeg<<<(EE + 255) / 256, 256, 0, stream>>>(ei, deg);
    k_scan1<<<nscan, 1024, 0, stream>>>(deg, row_ptr, aux);
    k_scan2<<<1, 64, 0, stream>>>(aux, nscan);
    k_scan3<<<(NN + 255) / 256, 256, 0, stream>>>(row_ptr, aux, wp);
    k_scatter<<<(EP + 255) / 256, 256, 0, stream>>>(ei, wp, esrc);

    k_prepva<<<(DIN * 16 + 255) / 256, 256, 0, stream>>>(W1, a1s, a1d, va);
    k_prepfrag<<<(17 * 2048 + 255) / 256, 256, 0, stream>>>(W1, va, w1frag);
    k_gemm1<<<(NW1 * 64 + 255) / 256, 256, 0, stream>>>(x, w1frag, h1b, al1sd);
    k_agg1<<<(NN * 64 + 255) / 256, 256, 0, stream>>>(row_ptr, esrc, h1b, al1sd, b1, helu_b);

    k_prepw2<<<(C1 * DOUT + 255) / 256, 256, 0, stream>>>(W2, W2b);
    k_gemm2<<<(NW1 * 64 + 255) / 256, 256, 0, stream>>>(helu_b, W2b, a2s, a2d, h2b, al2sb, al2db);
    k_agg2<<<(NN * 64 + 255) / 256, 256, 0, stream>>>(row_ptr, esrc, h2b, al2sb, al2db, b2, outp);
}